// Round 8
// baseline (561.479 us; speedup 1.0000x reference)
//
#include <hip/hip_runtime.h>
#include <hip/hip_bf16.h>
#include <math.h>

#define N_PATHS  200000
#define PATH_LEN 8
#define N_LINKS  20000
#define MAX_PL   100
#define DIM      16
#define ITERS    8

typedef __attribute__((ext_vector_type(8))) short bf16x8;
typedef __attribute__((ext_vector_type(4))) float f32x4;

// ws layout (bytes):
//   seq  : ushort[10][N_PATHS][16] = 64,000,000 (bf16 states; slots 1..7 steps, 8/9 prev/cur rotation)
//   ls   : float [N_LINKS][16]     =  1,280,000 (link_state fp32)
//   lrec : ushort[N_LINKS][32]     =  1,280,000 (64-B rec: per quad g: x[4g..4g+3] | mh[4g..4g+3])
//   p2lpE: uint  [N_LINKS*MAX_PL]  =  8,000,000
//   p2lpO: uint  [N_LINKS*MAX_PL]  =  8,000,000
#define SEQ_BYTES  64000000ull
#define LS_BYTES   1280000ull
#define LREC_BYTES 1280000ull
#define P2L_BYTES  8000000ull
#define SLOT_BYTES 6400000u   // N_PATHS * 16 * 2

__device__ __forceinline__ float fast_sigmoid(float x) {
    return __builtin_amdgcn_rcpf(1.0f + __expf(-x));
}
__device__ __forceinline__ float fast_tanh(float x) {
    float ax = fabsf(x);
    float t  = __expf(-2.0f * ax);
    float r  = (1.0f - t) * __builtin_amdgcn_rcpf(1.0f + t);
    return copysignf(r, x);
}
// softplus = max(x,0) + ln2 * log2(1 + exp2(-|x|*log2e))
__device__ __forceinline__ float fast_softplus(float x) {
    float e = __builtin_amdgcn_exp2f(-fabsf(x) * 1.44269504f);
    float lg = __builtin_amdgcn_logf(1.0f + e);   // log2
    return fmaxf(x, 0.0f) + 0.69314718f * lg;
}
__device__ __forceinline__ float bflo(unsigned int u) {
    union { unsigned int i; float f; } c; c.i = u << 16; return c.f;
}
__device__ __forceinline__ float bfhi(unsigned int u) {
    union { unsigned int i; float f; } c; c.i = u & 0xffff0000u; return c.f;
}
__device__ __forceinline__ unsigned int pk_bf16(float lo, float hi) {
    unsigned int r;
    asm("v_cvt_pk_bf16_f32 %0, %1, %2" : "=v"(r) : "v"(lo), "v"(hi));
    return r;
}
__device__ __forceinline__ unsigned short bf16_1(float v) {
    return (unsigned short)(pk_bf16(v, v) & 0xffffu);
}

union U8 { unsigned int u[4]; bf16x8 v; };

// ---------------- pack p2l into two slot-resolved variants ----------------
__global__ __launch_bounds__(256) void k_pack(const int* __restrict__ p2l,
                                              unsigned int* __restrict__ outE,
                                              unsigned int* __restrict__ outO)
{
    int i = blockIdx.x * 256 + threadIdx.x;
    if (i < N_LINKS * MAX_PL) {
        unsigned int pi = (unsigned int)p2l[2 * i];
        unsigned int si = (unsigned int)p2l[2 * i + 1];
        unsigned int sE = (si == 0) ? 8u : ((si == 8) ? 9u : si);
        unsigned int sO = (si == 0) ? 9u : ((si == 8) ? 8u : si);
        outE[i] = (sE << 18) | pi;
        outO[i] = (sO << 18) | pi;
    }
}

// ---------------- init: link load -> link_state -> ls + lrec ----------------
__global__ __launch_bounds__(64) void k_init_links(
    const float* __restrict__ traffic, const float* __restrict__ cap,
    const int* __restrict__ p2l,
    const float* __restrict__ le_w1, const float* __restrict__ le_b1,
    const float* __restrict__ le_w2, const float* __restrict__ le_b2,
    const float* __restrict__ kk, const float* __restrict__ pb,
    float* __restrict__ ls, unsigned short* __restrict__ lrec)
{
    int l = blockIdx.x;
    int lane = threadIdx.x;
    float s = 0.0f;
    for (int j = lane; j < MAX_PL; j += 64) {
        int p = p2l[(size_t)(l * MAX_PL + j) * 2 + 0];
        s += traffic[p];
    }
    #pragma unroll
    for (int off = 32; off > 0; off >>= 1) s += __shfl_xor(s, off);

    float c = cap[l];
    float f0 = c * 0.1f;
    float f1 = s / (c * 1e9f);

    float h1[DIM];
    #pragma unroll
    for (int d = 0; d < DIM; d++)
        h1[d] = fmaxf(f0 * le_w1[d] + f1 * le_w1[DIM + d] + le_b1[d], 0.0f);

    float h2[DIM];
    #pragma unroll
    for (int d = 0; d < DIM; d++) {
        float a = le_b2[d];
        #pragma unroll
        for (int k = 0; k < DIM; k++) a = fmaf(h1[k], le_w2[k * DIM + d], a);
        h2[d] = fmaxf(a, 0.0f);
    }
    if (lane < DIM) ls[(size_t)l * DIM + lane] = h2[lane];
    if (lane < DIM) {
        float mh = pb[32 + lane];
        #pragma unroll
        for (int k = 0; k < DIM; k++) mh = fmaf(h2[k], kk[k * 48 + 32 + lane], mh);
        unsigned short* rec = lrec + (size_t)l * 32;
        int q = lane >> 2, idx = lane & 3;
        rec[q * 8 + idx]     = bf16_1(h2[lane]);
        rec[q * 8 + 4 + idx] = bf16_1(mh);
    }
}

// ---------------- init: path_state -> seq slot 8 (bf16) ----------------
__global__ __launch_bounds__(256) void k_init_paths(
    const float* __restrict__ traffic, const float* __restrict__ packets,
    const float* __restrict__ pktsize, const float* __restrict__ ftype,
    const float* __restrict__ fe_w1, const float* __restrict__ fe_b1,
    const float* __restrict__ fe_w2, const float* __restrict__ fe_b2,
    unsigned short* __restrict__ seq)
{
    int p = blockIdx.x * blockDim.x + threadIdx.x;
    if (p >= N_PATHS) return;
    float f[5];
    f[0] = traffic[p] * 0.0001f;
    f[1] = packets[p] * 0.01f;
    f[2] = pktsize[p] * 0.001f;
    f[3] = ftype[p * 2 + 0];
    f[4] = ftype[p * 2 + 1];

    float h1[DIM];
    #pragma unroll
    for (int d = 0; d < DIM; d++) {
        float a = fe_b1[d];
        #pragma unroll
        for (int k = 0; k < 5; k++) a = fmaf(f[k], fe_w1[k * DIM + d], a);
        h1[d] = fmaxf(a, 0.0f);
    }
    float h2[DIM];
    #pragma unroll
    for (int d = 0; d < DIM; d++) {
        float a = fe_b2[d];
        #pragma unroll
        for (int k = 0; k < DIM; k++) a = fmaf(h1[k], fe_w2[k * DIM + d], a);
        h2[d] = fmaxf(a, 0.0f);
    }
    unsigned int pkd[8];
    #pragma unroll
    for (int q = 0; q < 8; q++) pkd[q] = pk_bf16(h2[2 * q], h2[2 * q + 1]);
    uint4* out = (uint4*)(seq + ((size_t)8 * N_PATHS + p) * DIM);
    out[0] = make_uint4(pkd[0], pkd[1], pkd[2], pkd[3]);
    out[1] = make_uint4(pkd[4], pkd[5], pkd[6], pkd[7]);
}

// ---------------- per-iteration: path GRU via MFMA, 16 paths/wave ----------------
__global__ __launch_bounds__(256) void k_paths(
    const int* __restrict__ l2p, const unsigned short* __restrict__ lrec,
    const float* __restrict__ rk, const float* __restrict__ kk,
    const float* __restrict__ b,
    unsigned short* __restrict__ seq, int ps, int cs)
{
    int l = threadIdx.x & 63;
    int wave = (blockIdx.x * 256 + threadIdx.x) >> 6;   // 0..12499 exact
    int pr = l & 15;
    int g  = l >> 4;
    int kq = g * 4;
    int p  = wave * 16 + pr;

    U8 Az, Ar, Ah;
    {
        #pragma unroll
        for (int i = 0; i < 2; i++) {
            int k0 = (kq + 2 * i) * 48, k1 = (kq + 2 * i + 1) * 48;
            Az.u[i]     = pk_bf16(rk[k0 + pr],      rk[k1 + pr]);
            Az.u[2 + i] = pk_bf16(kk[k0 + pr],      kk[k1 + pr]);
            Ar.u[i]     = pk_bf16(rk[k0 + 16 + pr], rk[k1 + 16 + pr]);
            Ar.u[2 + i] = pk_bf16(kk[k0 + 16 + pr], kk[k1 + 16 + pr]);
            Ah.u[i]     = pk_bf16(rk[k0 + 32 + pr], rk[k1 + 32 + pr]);
            Ah.u[2 + i] = 0;
        }
    }
    f32x4 Cz, Cr, Ch;
    #pragma unroll
    for (int r = 0; r < 4; r++) {
        Cz[r] = b[kq + r]      + b[48 + kq + r];
        Cr[r] = b[16 + kq + r] + b[64 + kq + r];
        Ch[r] = b[80 + kq + r];
    }

    int4 ia = *(const int4*)(l2p + (size_t)p * 8);
    int4 ib = *(const int4*)(l2p + (size_t)p * 8 + 4);
#define IDX(t) ((t) == 0 ? ia.x : (t) == 1 ? ia.y : (t) == 2 ? ia.z : (t) == 3 ? ia.w : \
                (t) == 4 ? ib.x : (t) == 5 ? ib.y : (t) == 6 ? ib.z : ib.w)

    const char* lrecc = (const char*)lrec;
    char* seqc = (char*)seq;
    unsigned g16 = (unsigned)(g * 16);
    unsigned sbase = (unsigned)p * 32u + (unsigned)(g * 8);
    unsigned csoff = (unsigned)cs * SLOT_BYTES + sbase;

    uint4 X[8];
    #pragma unroll
    for (int t = 0; t < 8; t++)
        X[t] = *(const uint4*)(lrecc + (unsigned)IDX(t) * 64u + g16);

    float h0, h1, h2, h3;
    U8 B;
    {
        uint2 hp = *(const uint2*)(seqc + ((unsigned)ps * SLOT_BYTES + sbase));
        h0 = bflo(hp.x); h1 = bfhi(hp.x); h2 = bflo(hp.y); h3 = bfhi(hp.y);
        B.u[0] = hp.x; B.u[1] = hp.y;
    }

#define STEPX(t, soff) { \
    B.u[2] = X[t].x; B.u[3] = X[t].y; \
    f32x4 az = __builtin_amdgcn_mfma_f32_16x16x32_bf16(Az.v, B.v, Cz, 0, 0, 0); \
    f32x4 ar = __builtin_amdgcn_mfma_f32_16x16x32_bf16(Ar.v, B.v, Cr, 0, 0, 0); \
    f32x4 ah = __builtin_amdgcn_mfma_f32_16x16x32_bf16(Ah.v, B.v, Ch, 0, 0, 0); \
    float z0 = fast_sigmoid(az[0]), z1 = fast_sigmoid(az[1]); \
    float z2 = fast_sigmoid(az[2]), z3 = fast_sigmoid(az[3]); \
    float r0 = fast_sigmoid(ar[0]), r1 = fast_sigmoid(ar[1]); \
    float r2 = fast_sigmoid(ar[2]), r3 = fast_sigmoid(ar[3]); \
    float q0 = fast_tanh(bflo(X[t].z) + r0 * ah[0]); \
    float q1 = fast_tanh(bfhi(X[t].z) + r1 * ah[1]); \
    float q2 = fast_tanh(bflo(X[t].w) + r2 * ah[2]); \
    float q3 = fast_tanh(bfhi(X[t].w) + r3 * ah[3]); \
    h0 = z0 * h0 + (1.0f - z0) * q0; \
    h1 = z1 * h1 + (1.0f - z1) * q1; \
    h2 = z2 * h2 + (1.0f - z2) * q2; \
    h3 = z3 * h3 + (1.0f - z3) * q3; \
    unsigned int p01 = pk_bf16(h0, h1), p23 = pk_bf16(h2, h3); \
    *(uint2*)(seqc + (soff)) = make_uint2(p01, p23); \
    B.u[0] = p01; B.u[1] = p23; }

    STEPX(0, 1u * SLOT_BYTES + sbase)
    STEPX(1, 2u * SLOT_BYTES + sbase)
    STEPX(2, 3u * SLOT_BYTES + sbase)
    STEPX(3, 4u * SLOT_BYTES + sbase)
    STEPX(4, 5u * SLOT_BYTES + sbase)
    STEPX(5, 6u * SLOT_BYTES + sbase)
    STEPX(6, 7u * SLOT_BYTES + sbase)
    STEPX(7, csoff)
#undef STEPX
}

// ---------------- final iteration: path GRU + fused readout, NO seq writes ----------------
// Per step: GRU as above, then one extra MFMA computes h1=relu(h@ro_w1+b1) for all
// 16 paths (A1=ro_w1^T rows 0..7, B=packed h, high-K zero). shfl_xor(16) assembles
// full fp32 h1 on lanes 0..15; 8->4->1 MLP + softplus + /cap in fp32 VALU.
__global__ __launch_bounds__(256) void k_paths_last(
    const int* __restrict__ l2p, const unsigned short* __restrict__ lrec,
    const float* __restrict__ rk, const float* __restrict__ kk,
    const float* __restrict__ b,
    const unsigned short* __restrict__ seq,
    const float* __restrict__ cap,
    const float* __restrict__ w1, const float* __restrict__ b1,
    const float* __restrict__ w2, const float* __restrict__ b2,
    const float* __restrict__ w3, const float* __restrict__ b3,
    float* __restrict__ out, int ps)
{
    int l = threadIdx.x & 63;
    int wave = (blockIdx.x * 256 + threadIdx.x) >> 6;
    int pr = l & 15;
    int g  = l >> 4;
    int kq = g * 4;
    int p  = wave * 16 + pr;

    U8 Az, Ar, Ah, A1;
    {
        #pragma unroll
        for (int i = 0; i < 2; i++) {
            int k0 = (kq + 2 * i) * 48, k1 = (kq + 2 * i + 1) * 48;
            Az.u[i]     = pk_bf16(rk[k0 + pr],      rk[k1 + pr]);
            Az.u[2 + i] = pk_bf16(kk[k0 + pr],      kk[k1 + pr]);
            Ar.u[i]     = pk_bf16(rk[k0 + 16 + pr], rk[k1 + 16 + pr]);
            Ar.u[2 + i] = pk_bf16(kk[k0 + 16 + pr], kk[k1 + 16 + pr]);
            Ah.u[i]     = pk_bf16(rk[k0 + 32 + pr], rk[k1 + 32 + pr]);
            Ah.u[2 + i] = 0;
            // readout layer 1: A1[m=pr][k] = w1[k][pr] for pr<8
            A1.u[i]     = (pr < 8) ? pk_bf16(w1[(kq + 2 * i) * 8 + pr],
                                             w1[(kq + 2 * i + 1) * 8 + pr]) : 0u;
            A1.u[2 + i] = 0;
        }
    }
    f32x4 Cz, Cr, Ch, C1;
    #pragma unroll
    for (int r = 0; r < 4; r++) {
        Cz[r] = b[kq + r]      + b[48 + kq + r];
        Cr[r] = b[16 + kq + r] + b[64 + kq + r];
        Ch[r] = b[80 + kq + r];
        C1[r] = (kq + r < 8) ? b1[kq + r] : 0.0f;
    }
    // fp32 readout tail weights (uniform scalar loads)
    float W2[8][4], B2v[4], W3[4], B3v;
    #pragma unroll
    for (int k = 0; k < 8; k++)
        #pragma unroll
        for (int j = 0; j < 4; j++) W2[k][j] = w2[k * 4 + j];
    #pragma unroll
    for (int j = 0; j < 4; j++) B2v[j] = b2[j];
    #pragma unroll
    for (int j = 0; j < 4; j++) W3[j] = w3[j];
    B3v = b3[0];

    int4 ia = *(const int4*)(l2p + (size_t)p * 8);
    int4 ib = *(const int4*)(l2p + (size_t)p * 8 + 4);

    const char* lrecc = (const char*)lrec;
    const char* seqc = (const char*)seq;
    unsigned g16 = (unsigned)(g * 16);
    unsigned sbase = (unsigned)p * 32u + (unsigned)(g * 8);

    uint4 X[8];
    float capv[8];
    #pragma unroll
    for (int t = 0; t < 8; t++) {
        int li = IDX(t);
        X[t] = *(const uint4*)(lrecc + (unsigned)li * 64u + g16);
        capv[t] = cap[li];
    }

    float h0, h1, h2, h3;
    U8 B;
    {
        uint2 hp = *(const uint2*)(seqc + ((unsigned)ps * SLOT_BYTES + sbase));
        h0 = bflo(hp.x); h1 = bfhi(hp.x); h2 = bflo(hp.y); h3 = bfhi(hp.y);
        B.u[0] = hp.x; B.u[1] = hp.y;
    }
    U8 Bro;
    Bro.u[2] = 0; Bro.u[3] = 0;
    float delay = 0.0f;

#define STEPL(t) { \
    B.u[2] = X[t].x; B.u[3] = X[t].y; \
    f32x4 az = __builtin_amdgcn_mfma_f32_16x16x32_bf16(Az.v, B.v, Cz, 0, 0, 0); \
    f32x4 ar = __builtin_amdgcn_mfma_f32_16x16x32_bf16(Ar.v, B.v, Cr, 0, 0, 0); \
    f32x4 ah = __builtin_amdgcn_mfma_f32_16x16x32_bf16(Ah.v, B.v, Ch, 0, 0, 0); \
    float z0 = fast_sigmoid(az[0]), z1 = fast_sigmoid(az[1]); \
    float z2 = fast_sigmoid(az[2]), z3 = fast_sigmoid(az[3]); \
    float r0 = fast_sigmoid(ar[0]), r1 = fast_sigmoid(ar[1]); \
    float r2 = fast_sigmoid(ar[2]), r3 = fast_sigmoid(ar[3]); \
    float q0 = fast_tanh(bflo(X[t].z) + r0 * ah[0]); \
    float q1 = fast_tanh(bfhi(X[t].z) + r1 * ah[1]); \
    float q2 = fast_tanh(bflo(X[t].w) + r2 * ah[2]); \
    float q3 = fast_tanh(bfhi(X[t].w) + r3 * ah[3]); \
    h0 = z0 * h0 + (1.0f - z0) * q0; \
    h1 = z1 * h1 + (1.0f - z1) * q1; \
    h2 = z2 * h2 + (1.0f - z2) * q2; \
    h3 = z3 * h3 + (1.0f - z3) * q3; \
    unsigned int p01 = pk_bf16(h0, h1), p23 = pk_bf16(h2, h3); \
    B.u[0] = p01; B.u[1] = p23; \
    Bro.u[0] = p01; Bro.u[1] = p23; \
    f32x4 d1 = __builtin_amdgcn_mfma_f32_16x16x32_bf16(A1.v, Bro.v, C1, 0, 0, 0); \
    float e0 = fmaxf(d1[0], 0.0f), e1 = fmaxf(d1[1], 0.0f); \
    float e2 = fmaxf(d1[2], 0.0f), e3 = fmaxf(d1[3], 0.0f); \
    float f0 = __shfl_xor(e0, 16), f1 = __shfl_xor(e1, 16); \
    float f2 = __shfl_xor(e2, 16), f3 = __shfl_xor(e3, 16); \
    float hh2[4]; \
    _Pragma("unroll") \
    for (int j = 0; j < 4; j++) { \
        float a2 = B2v[j]; \
        a2 = fmaf(e0, W2[0][j], a2); a2 = fmaf(e1, W2[1][j], a2); \
        a2 = fmaf(e2, W2[2][j], a2); a2 = fmaf(e3, W2[3][j], a2); \
        a2 = fmaf(f0, W2[4][j], a2); a2 = fmaf(f1, W2[5][j], a2); \
        a2 = fmaf(f2, W2[6][j], a2); a2 = fmaf(f3, W2[7][j], a2); \
        hh2[j] = fmaxf(a2, 0.0f); \
    } \
    float o = B3v; \
    o = fmaf(hh2[0], W3[0], o); o = fmaf(hh2[1], W3[1], o); \
    o = fmaf(hh2[2], W3[2], o); o = fmaf(hh2[3], W3[3], o); \
    o = fast_softplus(o); \
    delay += o * __builtin_amdgcn_rcpf(capv[t]); }

    STEPL(0) STEPL(1) STEPL(2) STEPL(3)
    STEPL(4) STEPL(5) STEPL(6) STEPL(7)
#undef STEPL
#undef IDX

    if (g == 0) out[p] = delay;
}

// ---------------- per-iteration: link aggregate + link GRU + lrec ----------------
__global__ __launch_bounds__(256) void k_links(
    const unsigned int* __restrict__ p2lp, const unsigned short* __restrict__ seq,
    const float* __restrict__ lk, const float* __restrict__ lrk,
    const float* __restrict__ lb,
    const float* __restrict__ kk, const float* __restrict__ pb,
    float* ls, unsigned short* __restrict__ lrec)
{
    int lane = threadIdx.x & 63;
    int l = blockIdx.x * 4 + (threadIdx.x >> 6);
    size_t base = (size_t)l * MAX_PL;
    int half = lane & 1;
    int r0 = lane >> 1;

    unsigned int e0 = p2lp[base + r0];
    unsigned int e1 = p2lp[base + r0 + 32];
    unsigned int e2 = p2lp[base + r0 + 64];

    const unsigned short* sh = seq + half * 8;
    unsigned int pi, si;
    pi = e0 & 0x3FFFFu; si = e0 >> 18;
    uint4 a0 = *(const uint4*)(sh + ((size_t)si * N_PATHS + pi) * DIM);
    pi = e1 & 0x3FFFFu; si = e1 >> 18;
    uint4 a1 = *(const uint4*)(sh + ((size_t)si * N_PATHS + pi) * DIM);
    pi = e2 & 0x3FFFFu; si = e2 >> 18;
    uint4 a2 = *(const uint4*)(sh + ((size_t)si * N_PATHS + pi) * DIM);

    float acc[8];
    #pragma unroll
    for (int i = 0; i < 8; i++) acc[i] = 0.0f;
    unsigned int selLo = 0x00003F80u;
    unsigned int selHi = 0x3F800000u;

#define DOTU(u, i0) \
    asm("v_dot2_f32_bf16 %0, %1, %2, %0" : "+v"(acc[i0]) : "v"(u), "v"(selLo)); \
    asm("v_dot2_f32_bf16 %0, %1, %2, %0" : "+v"(acc[i0 + 1]) : "v"(u), "v"(selHi));
#define DOT8(a) DOTU(a.x, 0) DOTU(a.y, 2) DOTU(a.z, 4) DOTU(a.w, 6)

    DOT8(a0) DOT8(a1) DOT8(a2)
    if (r0 < 4) {
        unsigned int e3 = p2lp[base + r0 + 96];
        pi = e3 & 0x3FFFFu; si = e3 >> 18;
        uint4 a3 = *(const uint4*)(sh + ((size_t)si * N_PATHS + pi) * DIM);
        DOT8(a3)
    }
#undef DOTU
#undef DOT8

    float v4[4];
    {
        int sel = (lane & 2) ? 4 : 0;
        #pragma unroll
        for (int i = 0; i < 4; i++)
            v4[i] = acc[sel + i] + __shfl_xor(acc[(4 - sel) + i], 2);
    }
    float v2[2];
    {
        int sel = (lane & 4) ? 2 : 0;
        #pragma unroll
        for (int i = 0; i < 2; i++)
            v2[i] = v4[sel + i] + __shfl_xor(v4[(2 - sel) + i], 4);
    }
    float s;
    {
        int sel = (lane & 8) ? 1 : 0;
        s = v2[sel] + __shfl_xor(v2[1 - sel], 8);
    }
    s += __shfl_xor(s, 16);
    s += __shfl_xor(s, 32);

    float accf[16];
    #pragma unroll
    for (int k = 0; k < 16; k++) {
        int src = ((k >> 3) & 1) | (((k >> 2) & 1) << 1) | (((k >> 1) & 1) << 2) | ((k & 1) << 3);
        accf[k] = __shfl(s, src);
    }

    float h[DIM];
    #pragma unroll
    for (int d = 0; d < DIM; d++) h[d] = ls[(size_t)l * DIM + d];

    int j = (lane < 48) ? lane : 0;
    float mx = lb[j];
    float mi = lb[48 + j];
    #pragma unroll
    for (int k = 0; k < DIM; k++) {
        mx = fmaf(accf[k], lk[k * 48 + j], mx);
        mi = fmaf(h[k],   lrk[k * 48 + j], mi);
    }

    int d = lane & 15;
    float xz = __shfl(mx, d),      rz = __shfl(mi, d);
    float xr = __shfl(mx, d + 16), rr = __shfl(mi, d + 16);
    float xh = __shfl(mx, d + 32), rh = __shfl(mi, d + 32);
    float z  = fast_sigmoid(xz + rz);
    float r  = fast_sigmoid(xr + rr);
    float hh = fast_tanh(xh + r * rh);
    float hn = z * h[d] + (1.0f - z) * hh;

    if (lane < DIM) ls[(size_t)l * DIM + lane] = hn;

    float hf[DIM];
    #pragma unroll
    for (int k = 0; k < DIM; k++) hf[k] = __shfl(hn, k);
    if (lane < DIM) {
        float mh = pb[32 + lane];
        #pragma unroll
        for (int k = 0; k < DIM; k++) mh = fmaf(hf[k], kk[k * 48 + 32 + lane], mh);
        unsigned short* rec = lrec + (size_t)l * 32;
        int q = lane >> 2, idx = lane & 3;
        rec[q * 8 + idx]     = bf16_1(hn);
        rec[q * 8 + 4 + idx] = bf16_1(mh);
    }
}

extern "C" void kernel_launch(void* const* d_in, const int* in_sizes, int n_in,
                              void* d_out, int out_size, void* d_ws, size_t ws_size,
                              hipStream_t stream)
{
    const float* flow_traffic = (const float*)d_in[0];
    const float* flow_packets = (const float*)d_in[1];
    const float* flow_pktsize = (const float*)d_in[2];
    const float* flow_type    = (const float*)d_in[3];
    const float* link_cap     = (const float*)d_in[4];
    const int*   l2p          = (const int*)d_in[5];
    const int*   p2l          = (const int*)d_in[6];
    const float* fe_w1 = (const float*)d_in[7];
    const float* fe_b1 = (const float*)d_in[8];
    const float* fe_w2 = (const float*)d_in[9];
    const float* fe_b2 = (const float*)d_in[10];
    const float* le_w1 = (const float*)d_in[11];
    const float* le_b1 = (const float*)d_in[12];
    const float* le_w2 = (const float*)d_in[13];
    const float* le_b2 = (const float*)d_in[14];
    const float* pgru_k  = (const float*)d_in[15];
    const float* pgru_rk = (const float*)d_in[16];
    const float* pgru_b  = (const float*)d_in[17];
    const float* lgru_k  = (const float*)d_in[18];
    const float* lgru_rk = (const float*)d_in[19];
    const float* lgru_b  = (const float*)d_in[20];
    const float* ro_w1 = (const float*)d_in[21];
    const float* ro_b1 = (const float*)d_in[22];
    const float* ro_w2 = (const float*)d_in[23];
    const float* ro_b2 = (const float*)d_in[24];
    const float* ro_w3 = (const float*)d_in[25];
    const float* ro_b3 = (const float*)d_in[26];
    float* out = (float*)d_out;

    char* ws = (char*)d_ws;
    unsigned short* seq   = (unsigned short*)ws;
    float*          ls    = (float*)(ws + SEQ_BYTES);
    unsigned short* lrec  = (unsigned short*)(ws + SEQ_BYTES + LS_BYTES);
    unsigned int*   p2lpE = (unsigned int*)(ws + SEQ_BYTES + LS_BYTES + LREC_BYTES);
    unsigned int*   p2lpO = (unsigned int*)(ws + SEQ_BYTES + LS_BYTES + LREC_BYTES + P2L_BYTES);

    k_pack<<<(N_LINKS * MAX_PL + 255) / 256, 256, 0, stream>>>(p2l, p2lpE, p2lpO);
    k_init_links<<<N_LINKS, 64, 0, stream>>>(flow_traffic, link_cap, p2l,
        le_w1, le_b1, le_w2, le_b2, pgru_k, pgru_b, ls, lrec);
    k_init_paths<<<(N_PATHS + 255) / 256, 256, 0, stream>>>(flow_traffic,
        flow_packets, flow_pktsize, flow_type, fe_w1, fe_b1, fe_w2, fe_b2, seq);

    for (int it = 0; it < ITERS - 1; ++it) {
        int ps = (it & 1) ? 9 : 8;
        int cs = (it & 1) ? 8 : 9;
        k_paths<<<(N_PATHS / 16) / 4, 256, 0, stream>>>(l2p, lrec, pgru_rk,
            pgru_k, pgru_b, seq, ps, cs);
        k_links<<<N_LINKS / 4, 256, 0, stream>>>((it & 1) ? p2lpO : p2lpE,
            seq, lgru_k, lgru_rk, lgru_b, pgru_k, pgru_b, ls, lrec);
    }
    // final iteration (it=7, ps=9): GRU + fused readout, no seq writes, no k_links
    k_paths_last<<<(N_PATHS / 16) / 4, 256, 0, stream>>>(l2p, lrec, pgru_rk,
        pgru_k, pgru_b, seq, link_cap,
        ro_w1, ro_b1, ro_w2, ro_b2, ro_w3, ro_b3, out, 9);
}

// Round 9
// 538.046 us; speedup vs baseline: 1.0436x; 1.0436x over previous
//
#include <hip/hip_runtime.h>
#include <hip/hip_bf16.h>
#include <math.h>

#define N_PATHS  200000
#define PATH_LEN 8
#define N_LINKS  20000
#define MAX_PL   100
#define DIM      16
#define ITERS    8

typedef __attribute__((ext_vector_type(8))) short bf16x8;
typedef __attribute__((ext_vector_type(4))) float f32x4;

// ws layout (bytes):
//   seq  : ushort[10][N_PATHS][16] = 64,000,000 (bf16 states; slots 1..7 steps, 8/9 prev/cur rotation)
//   ls   : float [N_LINKS][16]     =  1,280,000 (link_state fp32)
//   lrec : ushort[N_LINKS][32]     =  1,280,000 (64-B rec per link: quad g: x[4g..4g+3] | mh[4g..4g+3])
//   p2lpE: uint  [N_LINKS*MAX_PL]  =  8,000,000
//   p2lpO: uint  [N_LINKS*MAX_PL]  =  8,000,000
//   wtab : uint4 [8][64]           =      8,192 (per-lane MFMA frags/biases: Az Ar Ah A1 Cz Cr Ch C1)
#define SEQ_BYTES  64000000ull
#define LS_BYTES   1280000ull
#define LREC_BYTES 1280000ull
#define P2L_BYTES  8000000ull
#define SLOT_BYTES 6400000u   // N_PATHS * 16 * 2

__device__ __forceinline__ float fast_sigmoid(float x) {
    return __builtin_amdgcn_rcpf(1.0f + __expf(-x));
}
__device__ __forceinline__ float fast_tanh(float x) {
    float ax = fabsf(x);
    float t  = __expf(-2.0f * ax);
    float r  = (1.0f - t) * __builtin_amdgcn_rcpf(1.0f + t);
    return copysignf(r, x);
}
// softplus = max(x,0) + ln2 * log2(1 + exp2(-|x|*log2e))
__device__ __forceinline__ float fast_softplus(float x) {
    float e = __builtin_amdgcn_exp2f(-fabsf(x) * 1.44269504f);
    float lg = __builtin_amdgcn_logf(1.0f + e);   // log2
    return fmaxf(x, 0.0f) + 0.69314718f * lg;
}
__device__ __forceinline__ float bflo(unsigned int u) {
    union { unsigned int i; float f; } c; c.i = u << 16; return c.f;
}
__device__ __forceinline__ float bfhi(unsigned int u) {
    union { unsigned int i; float f; } c; c.i = u & 0xffff0000u; return c.f;
}
__device__ __forceinline__ unsigned int pk_bf16(float lo, float hi) {
    unsigned int r;
    asm("v_cvt_pk_bf16_f32 %0, %1, %2" : "=v"(r) : "v"(lo), "v"(hi));
    return r;
}
__device__ __forceinline__ unsigned short bf16_1(float v) {
    return (unsigned short)(pk_bf16(v, v) & 0xffffu);
}

union U8 { unsigned int u[4]; bf16x8 v; };
union UF4 { uint4 u; f32x4 f; };

// ---------------- pack p2l into two slot-resolved variants ----------------
__global__ __launch_bounds__(256) void k_pack(const int* __restrict__ p2l,
                                              unsigned int* __restrict__ outE,
                                              unsigned int* __restrict__ outO)
{
    int i = blockIdx.x * 256 + threadIdx.x;
    if (i < N_LINKS * MAX_PL) {
        unsigned int pi = (unsigned int)p2l[2 * i];
        unsigned int si = (unsigned int)p2l[2 * i + 1];
        unsigned int sE = (si == 0) ? 8u : ((si == 8) ? 9u : si);
        unsigned int sO = (si == 0) ? 9u : ((si == 8) ? 8u : si);
        outE[i] = (sE << 18) | pi;
        outO[i] = (sO << 18) | pi;
    }
}

// ---------------- init: per-lane MFMA fragment/bias table ----------------
// wtab[k][lane], k: 0=Az 1=Ar 2=Ah 3=A1 4=Cz 5=Cr 6=Ch 7=C1
__global__ __launch_bounds__(64) void k_init_wtab(
    const float* __restrict__ rk, const float* __restrict__ kk,
    const float* __restrict__ b,
    const float* __restrict__ w1, const float* __restrict__ b1,
    uint4* __restrict__ wtab)
{
    int l = threadIdx.x;
    int pr = l & 15, g = l >> 4, kq = g * 4;
    U8 Az, Ar, Ah, A1;
    #pragma unroll
    for (int i = 0; i < 2; i++) {
        int k0 = (kq + 2 * i) * 48, k1 = (kq + 2 * i + 1) * 48;
        Az.u[i]     = pk_bf16(rk[k0 + pr],      rk[k1 + pr]);
        Az.u[2 + i] = pk_bf16(kk[k0 + pr],      kk[k1 + pr]);
        Ar.u[i]     = pk_bf16(rk[k0 + 16 + pr], rk[k1 + 16 + pr]);
        Ar.u[2 + i] = pk_bf16(kk[k0 + 16 + pr], kk[k1 + 16 + pr]);
        Ah.u[i]     = pk_bf16(rk[k0 + 32 + pr], rk[k1 + 32 + pr]);
        Ah.u[2 + i] = 0;
        A1.u[i]     = (pr < 8) ? pk_bf16(w1[(kq + 2 * i) * 8 + pr],
                                         w1[(kq + 2 * i + 1) * 8 + pr]) : 0u;
        A1.u[2 + i] = 0;
    }
    UF4 Cz, Cr, Ch, C1;
    #pragma unroll
    for (int r = 0; r < 4; r++) {
        Cz.f[r] = b[kq + r]      + b[48 + kq + r];
        Cr.f[r] = b[16 + kq + r] + b[64 + kq + r];
        Ch.f[r] = b[80 + kq + r];
        C1.f[r] = (kq + r < 8) ? b1[kq + r] : 0.0f;
    }
    wtab[0 * 64 + l] = make_uint4(Az.u[0], Az.u[1], Az.u[2], Az.u[3]);
    wtab[1 * 64 + l] = make_uint4(Ar.u[0], Ar.u[1], Ar.u[2], Ar.u[3]);
    wtab[2 * 64 + l] = make_uint4(Ah.u[0], Ah.u[1], Ah.u[2], Ah.u[3]);
    wtab[3 * 64 + l] = make_uint4(A1.u[0], A1.u[1], A1.u[2], A1.u[3]);
    wtab[4 * 64 + l] = Cz.u;
    wtab[5 * 64 + l] = Cr.u;
    wtab[6 * 64 + l] = Ch.u;
    wtab[7 * 64 + l] = C1.u;
}

// ---------------- init: link load -> link_state -> ls + lrec ----------------
__global__ __launch_bounds__(64) void k_init_links(
    const float* __restrict__ traffic, const float* __restrict__ cap,
    const int* __restrict__ p2l,
    const float* __restrict__ le_w1, const float* __restrict__ le_b1,
    const float* __restrict__ le_w2, const float* __restrict__ le_b2,
    const float* __restrict__ kk, const float* __restrict__ pb,
    float* __restrict__ ls, unsigned short* __restrict__ lrec)
{
    int l = blockIdx.x;
    int lane = threadIdx.x;
    float s = 0.0f;
    for (int j = lane; j < MAX_PL; j += 64) {
        int p = p2l[(size_t)(l * MAX_PL + j) * 2 + 0];
        s += traffic[p];
    }
    #pragma unroll
    for (int off = 32; off > 0; off >>= 1) s += __shfl_xor(s, off);

    float c = cap[l];
    float f0 = c * 0.1f;
    float f1 = s / (c * 1e9f);

    float h1[DIM];
    #pragma unroll
    for (int d = 0; d < DIM; d++)
        h1[d] = fmaxf(f0 * le_w1[d] + f1 * le_w1[DIM + d] + le_b1[d], 0.0f);

    float h2[DIM];
    #pragma unroll
    for (int d = 0; d < DIM; d++) {
        float a = le_b2[d];
        #pragma unroll
        for (int k = 0; k < DIM; k++) a = fmaf(h1[k], le_w2[k * DIM + d], a);
        h2[d] = fmaxf(a, 0.0f);
    }
    if (lane < DIM) ls[(size_t)l * DIM + lane] = h2[lane];
    if (lane < DIM) {
        float mh = pb[32 + lane];
        #pragma unroll
        for (int k = 0; k < DIM; k++) mh = fmaf(h2[k], kk[k * 48 + 32 + lane], mh);
        unsigned short* rec = lrec + (size_t)l * 32;
        int q = lane >> 2, idx = lane & 3;
        rec[q * 8 + idx]     = bf16_1(h2[lane]);
        rec[q * 8 + 4 + idx] = bf16_1(mh);
    }
}

// ---------------- init: path_state -> seq slot 8 (bf16) ----------------
__global__ __launch_bounds__(256) void k_init_paths(
    const float* __restrict__ traffic, const float* __restrict__ packets,
    const float* __restrict__ pktsize, const float* __restrict__ ftype,
    const float* __restrict__ fe_w1, const float* __restrict__ fe_b1,
    const float* __restrict__ fe_w2, const float* __restrict__ fe_b2,
    unsigned short* __restrict__ seq)
{
    int p = blockIdx.x * blockDim.x + threadIdx.x;
    if (p >= N_PATHS) return;
    float f[5];
    f[0] = traffic[p] * 0.0001f;
    f[1] = packets[p] * 0.01f;
    f[2] = pktsize[p] * 0.001f;
    f[3] = ftype[p * 2 + 0];
    f[4] = ftype[p * 2 + 1];

    float h1[DIM];
    #pragma unroll
    for (int d = 0; d < DIM; d++) {
        float a = fe_b1[d];
        #pragma unroll
        for (int k = 0; k < 5; k++) a = fmaf(f[k], fe_w1[k * DIM + d], a);
        h1[d] = fmaxf(a, 0.0f);
    }
    float h2[DIM];
    #pragma unroll
    for (int d = 0; d < DIM; d++) {
        float a = fe_b2[d];
        #pragma unroll
        for (int k = 0; k < DIM; k++) a = fmaf(h1[k], fe_w2[k * DIM + d], a);
        h2[d] = fmaxf(a, 0.0f);
    }
    unsigned int pkd[8];
    #pragma unroll
    for (int q = 0; q < 8; q++) pkd[q] = pk_bf16(h2[2 * q], h2[2 * q + 1]);
    uint4* out = (uint4*)(seq + ((size_t)8 * N_PATHS + p) * DIM);
    out[0] = make_uint4(pkd[0], pkd[1], pkd[2], pkd[3]);
    out[1] = make_uint4(pkd[4], pkd[5], pkd[6], pkd[7]);
}

// ---------------- per-iteration: path GRU via MFMA, 16 paths/wave ----------------
__global__ __launch_bounds__(256, 8) void k_paths(
    const int* __restrict__ l2p, const unsigned short* __restrict__ lrec,
    const uint4* __restrict__ wtab,
    unsigned short* __restrict__ seq, int ps, int cs)
{
    int l = threadIdx.x & 63;
    int wave = (blockIdx.x * 256 + threadIdx.x) >> 6;   // 0..12499 exact
    int pr = l & 15;
    int g  = l >> 4;
    int p  = wave * 16 + pr;

    // per-lane constant frags/biases: 6 coalesced 16-B loads
    U8 Az, Ar, Ah;
    {
        uint4 a = wtab[0 * 64 + l], r = wtab[1 * 64 + l], h = wtab[2 * 64 + l];
        Az.u[0] = a.x; Az.u[1] = a.y; Az.u[2] = a.z; Az.u[3] = a.w;
        Ar.u[0] = r.x; Ar.u[1] = r.y; Ar.u[2] = r.z; Ar.u[3] = r.w;
        Ah.u[0] = h.x; Ah.u[1] = h.y; Ah.u[2] = h.z; Ah.u[3] = h.w;
    }
    UF4 Czu, Cru, Chu;
    Czu.u = wtab[4 * 64 + l]; Cru.u = wtab[5 * 64 + l]; Chu.u = wtab[6 * 64 + l];
    f32x4 Cz = Czu.f, Cr = Cru.f, Ch = Chu.f;

    int4 ia = *(const int4*)(l2p + (size_t)p * 8);
    int4 ib = *(const int4*)(l2p + (size_t)p * 8 + 4);
#define IDX(t) ((t) == 0 ? ia.x : (t) == 1 ? ia.y : (t) == 2 ? ia.z : (t) == 3 ? ia.w : \
                (t) == 4 ? ib.x : (t) == 5 ? ib.y : (t) == 6 ? ib.z : ib.w)

    const char* lrecc = (const char*)lrec;
    char* seqc = (char*)seq;
    unsigned g16 = (unsigned)(g * 16);
    unsigned sbase = (unsigned)p * 32u + (unsigned)(g * 8);
    unsigned csoff = (unsigned)cs * SLOT_BYTES + sbase;

    uint4 X[8];
    #pragma unroll
    for (int t = 0; t < 8; t++)
        X[t] = *(const uint4*)(lrecc + (unsigned)IDX(t) * 64u + g16);

    float h0, h1, h2, h3;
    U8 B;
    {
        uint2 hp = *(const uint2*)(seqc + ((unsigned)ps * SLOT_BYTES + sbase));
        h0 = bflo(hp.x); h1 = bfhi(hp.x); h2 = bflo(hp.y); h3 = bfhi(hp.y);
        B.u[0] = hp.x; B.u[1] = hp.y;
    }

#define STEPX(t, soff) { \
    B.u[2] = X[t].x; B.u[3] = X[t].y; \
    f32x4 az = __builtin_amdgcn_mfma_f32_16x16x32_bf16(Az.v, B.v, Cz, 0, 0, 0); \
    f32x4 ar = __builtin_amdgcn_mfma_f32_16x16x32_bf16(Ar.v, B.v, Cr, 0, 0, 0); \
    f32x4 ah = __builtin_amdgcn_mfma_f32_16x16x32_bf16(Ah.v, B.v, Ch, 0, 0, 0); \
    float z0 = fast_sigmoid(az[0]), z1 = fast_sigmoid(az[1]); \
    float z2 = fast_sigmoid(az[2]), z3 = fast_sigmoid(az[3]); \
    float r0 = fast_sigmoid(ar[0]), r1 = fast_sigmoid(ar[1]); \
    float r2 = fast_sigmoid(ar[2]), r3 = fast_sigmoid(ar[3]); \
    float q0 = fast_tanh(bflo(X[t].z) + r0 * ah[0]); \
    float q1 = fast_tanh(bfhi(X[t].z) + r1 * ah[1]); \
    float q2 = fast_tanh(bflo(X[t].w) + r2 * ah[2]); \
    float q3 = fast_tanh(bfhi(X[t].w) + r3 * ah[3]); \
    h0 = z0 * h0 + (1.0f - z0) * q0; \
    h1 = z1 * h1 + (1.0f - z1) * q1; \
    h2 = z2 * h2 + (1.0f - z2) * q2; \
    h3 = z3 * h3 + (1.0f - z3) * q3; \
    unsigned int p01 = pk_bf16(h0, h1), p23 = pk_bf16(h2, h3); \
    *(uint2*)(seqc + (soff)) = make_uint2(p01, p23); \
    B.u[0] = p01; B.u[1] = p23; }

    STEPX(0, 1u * SLOT_BYTES + sbase)
    STEPX(1, 2u * SLOT_BYTES + sbase)
    STEPX(2, 3u * SLOT_BYTES + sbase)
    STEPX(3, 4u * SLOT_BYTES + sbase)
    STEPX(4, 5u * SLOT_BYTES + sbase)
    STEPX(5, 6u * SLOT_BYTES + sbase)
    STEPX(6, 7u * SLOT_BYTES + sbase)
    STEPX(7, csoff)
#undef STEPX
}

// ---------------- final iteration: path GRU + fused readout, NO seq writes ----------------
__global__ __launch_bounds__(256) void k_paths_last(
    const int* __restrict__ l2p, const unsigned short* __restrict__ lrec,
    const uint4* __restrict__ wtab,
    const unsigned short* __restrict__ seq,
    const float* __restrict__ cap,
    const float* __restrict__ w2, const float* __restrict__ b2,
    const float* __restrict__ w3, const float* __restrict__ b3,
    float* __restrict__ out, int ps)
{
    int l = threadIdx.x & 63;
    int wave = (blockIdx.x * 256 + threadIdx.x) >> 6;
    int pr = l & 15;
    int g  = l >> 4;
    int p  = wave * 16 + pr;

    U8 Az, Ar, Ah, A1;
    {
        uint4 a = wtab[0 * 64 + l], r = wtab[1 * 64 + l];
        uint4 h = wtab[2 * 64 + l], o1 = wtab[3 * 64 + l];
        Az.u[0] = a.x; Az.u[1] = a.y; Az.u[2] = a.z; Az.u[3] = a.w;
        Ar.u[0] = r.x; Ar.u[1] = r.y; Ar.u[2] = r.z; Ar.u[3] = r.w;
        Ah.u[0] = h.x; Ah.u[1] = h.y; Ah.u[2] = h.z; Ah.u[3] = h.w;
        A1.u[0] = o1.x; A1.u[1] = o1.y; A1.u[2] = o1.z; A1.u[3] = o1.w;
    }
    UF4 Czu, Cru, Chu, C1u;
    Czu.u = wtab[4 * 64 + l]; Cru.u = wtab[5 * 64 + l];
    Chu.u = wtab[6 * 64 + l]; C1u.u = wtab[7 * 64 + l];
    f32x4 Cz = Czu.f, Cr = Cru.f, Ch = Chu.f, C1 = C1u.f;

    float W2[8][4], B2v[4], W3[4], B3v;
    #pragma unroll
    for (int k = 0; k < 8; k++)
        #pragma unroll
        for (int j = 0; j < 4; j++) W2[k][j] = w2[k * 4 + j];
    #pragma unroll
    for (int j = 0; j < 4; j++) B2v[j] = b2[j];
    #pragma unroll
    for (int j = 0; j < 4; j++) W3[j] = w3[j];
    B3v = b3[0];

    int4 ia = *(const int4*)(l2p + (size_t)p * 8);
    int4 ib = *(const int4*)(l2p + (size_t)p * 8 + 4);

    const char* lrecc = (const char*)lrec;
    const char* seqc = (const char*)seq;
    unsigned g16 = (unsigned)(g * 16);
    unsigned sbase = (unsigned)p * 32u + (unsigned)(g * 8);

    uint4 X[8];
    float capv[8];
    #pragma unroll
    for (int t = 0; t < 8; t++) {
        int li = IDX(t);
        X[t] = *(const uint4*)(lrecc + (unsigned)li * 64u + g16);
        capv[t] = cap[li];
    }

    float h0, h1, h2, h3;
    U8 B;
    {
        uint2 hp = *(const uint2*)(seqc + ((unsigned)ps * SLOT_BYTES + sbase));
        h0 = bflo(hp.x); h1 = bfhi(hp.x); h2 = bflo(hp.y); h3 = bfhi(hp.y);
        B.u[0] = hp.x; B.u[1] = hp.y;
    }
    U8 Bro;
    Bro.u[2] = 0; Bro.u[3] = 0;
    float delay = 0.0f;

#define STEPL(t) { \
    B.u[2] = X[t].x; B.u[3] = X[t].y; \
    f32x4 az = __builtin_amdgcn_mfma_f32_16x16x32_bf16(Az.v, B.v, Cz, 0, 0, 0); \
    f32x4 ar = __builtin_amdgcn_mfma_f32_16x16x32_bf16(Ar.v, B.v, Cr, 0, 0, 0); \
    f32x4 ah = __builtin_amdgcn_mfma_f32_16x16x32_bf16(Ah.v, B.v, Ch, 0, 0, 0); \
    float z0 = fast_sigmoid(az[0]), z1 = fast_sigmoid(az[1]); \
    float z2 = fast_sigmoid(az[2]), z3 = fast_sigmoid(az[3]); \
    float r0 = fast_sigmoid(ar[0]), r1 = fast_sigmoid(ar[1]); \
    float r2 = fast_sigmoid(ar[2]), r3 = fast_sigmoid(ar[3]); \
    float q0 = fast_tanh(bflo(X[t].z) + r0 * ah[0]); \
    float q1 = fast_tanh(bfhi(X[t].z) + r1 * ah[1]); \
    float q2 = fast_tanh(bflo(X[t].w) + r2 * ah[2]); \
    float q3 = fast_tanh(bfhi(X[t].w) + r3 * ah[3]); \
    h0 = z0 * h0 + (1.0f - z0) * q0; \
    h1 = z1 * h1 + (1.0f - z1) * q1; \
    h2 = z2 * h2 + (1.0f - z2) * q2; \
    h3 = z3 * h3 + (1.0f - z3) * q3; \
    unsigned int p01 = pk_bf16(h0, h1), p23 = pk_bf16(h2, h3); \
    B.u[0] = p01; B.u[1] = p23; \
    Bro.u[0] = p01; Bro.u[1] = p23; \
    f32x4 d1 = __builtin_amdgcn_mfma_f32_16x16x32_bf16(A1.v, Bro.v, C1, 0, 0, 0); \
    float e0 = fmaxf(d1[0], 0.0f), e1 = fmaxf(d1[1], 0.0f); \
    float e2 = fmaxf(d1[2], 0.0f), e3 = fmaxf(d1[3], 0.0f); \
    float f0 = __shfl_xor(e0, 16), f1 = __shfl_xor(e1, 16); \
    float f2 = __shfl_xor(e2, 16), f3 = __shfl_xor(e3, 16); \
    float hh2[4]; \
    _Pragma("unroll") \
    for (int j = 0; j < 4; j++) { \
        float a2 = B2v[j]; \
        a2 = fmaf(e0, W2[0][j], a2); a2 = fmaf(e1, W2[1][j], a2); \
        a2 = fmaf(e2, W2[2][j], a2); a2 = fmaf(e3, W2[3][j], a2); \
        a2 = fmaf(f0, W2[4][j], a2); a2 = fmaf(f1, W2[5][j], a2); \
        a2 = fmaf(f2, W2[6][j], a2); a2 = fmaf(f3, W2[7][j], a2); \
        hh2[j] = fmaxf(a2, 0.0f); \
    } \
    float o = B3v; \
    o = fmaf(hh2[0], W3[0], o); o = fmaf(hh2[1], W3[1], o); \
    o = fmaf(hh2[2], W3[2], o); o = fmaf(hh2[3], W3[3], o); \
    o = fast_softplus(o); \
    delay += o * __builtin_amdgcn_rcpf(capv[t]); }

    STEPL(0) STEPL(1) STEPL(2) STEPL(3)
    STEPL(4) STEPL(5) STEPL(6) STEPL(7)
#undef STEPL
#undef IDX

    if (g == 0) out[p] = delay;
}

// ---------------- per-iteration: link aggregate + link GRU + lrec ----------------
__global__ __launch_bounds__(256) void k_links(
    const unsigned int* __restrict__ p2lp, const unsigned short* __restrict__ seq,
    const float* __restrict__ lk, const float* __restrict__ lrk,
    const float* __restrict__ lb,
    const float* __restrict__ kk, const float* __restrict__ pb,
    float* ls, unsigned short* __restrict__ lrec)
{
    int lane = threadIdx.x & 63;
    int l = blockIdx.x * 4 + (threadIdx.x >> 6);
    size_t base = (size_t)l * MAX_PL;
    int half = lane & 1;
    int r0 = lane >> 1;

    unsigned int e0 = p2lp[base + r0];
    unsigned int e1 = p2lp[base + r0 + 32];
    unsigned int e2 = p2lp[base + r0 + 64];

    const unsigned short* sh = seq + half * 8;
    unsigned int pi, si;
    pi = e0 & 0x3FFFFu; si = e0 >> 18;
    uint4 a0 = *(const uint4*)(sh + ((size_t)si * N_PATHS + pi) * DIM);
    pi = e1 & 0x3FFFFu; si = e1 >> 18;
    uint4 a1 = *(const uint4*)(sh + ((size_t)si * N_PATHS + pi) * DIM);
    pi = e2 & 0x3FFFFu; si = e2 >> 18;
    uint4 a2 = *(const uint4*)(sh + ((size_t)si * N_PATHS + pi) * DIM);

    float acc[8];
    #pragma unroll
    for (int i = 0; i < 8; i++) acc[i] = 0.0f;
    unsigned int selLo = 0x00003F80u;
    unsigned int selHi = 0x3F800000u;

#define DOTU(u, i0) \
    asm("v_dot2_f32_bf16 %0, %1, %2, %0" : "+v"(acc[i0]) : "v"(u), "v"(selLo)); \
    asm("v_dot2_f32_bf16 %0, %1, %2, %0" : "+v"(acc[i0 + 1]) : "v"(u), "v"(selHi));
#define DOT8(a) DOTU(a.x, 0) DOTU(a.y, 2) DOTU(a.z, 4) DOTU(a.w, 6)

    DOT8(a0) DOT8(a1) DOT8(a2)
    if (r0 < 4) {
        unsigned int e3 = p2lp[base + r0 + 96];
        pi = e3 & 0x3FFFFu; si = e3 >> 18;
        uint4 a3 = *(const uint4*)(sh + ((size_t)si * N_PATHS + pi) * DIM);
        DOT8(a3)
    }
#undef DOTU
#undef DOT8

    float v4[4];
    {
        int sel = (lane & 2) ? 4 : 0;
        #pragma unroll
        for (int i = 0; i < 4; i++)
            v4[i] = acc[sel + i] + __shfl_xor(acc[(4 - sel) + i], 2);
    }
    float v2[2];
    {
        int sel = (lane & 4) ? 2 : 0;
        #pragma unroll
        for (int i = 0; i < 2; i++)
            v2[i] = v4[sel + i] + __shfl_xor(v4[(2 - sel) + i], 4);
    }
    float s;
    {
        int sel = (lane & 8) ? 1 : 0;
        s = v2[sel] + __shfl_xor(v2[1 - sel], 8);
    }
    s += __shfl_xor(s, 16);
    s += __shfl_xor(s, 32);

    float accf[16];
    #pragma unroll
    for (int k = 0; k < 16; k++) {
        int src = ((k >> 3) & 1) | (((k >> 2) & 1) << 1) | (((k >> 1) & 1) << 2) | ((k & 1) << 3);
        accf[k] = __shfl(s, src);
    }

    float h[DIM];
    #pragma unroll
    for (int d = 0; d < DIM; d++) h[d] = ls[(size_t)l * DIM + d];

    int j = (lane < 48) ? lane : 0;
    float mx = lb[j];
    float mi = lb[48 + j];
    #pragma unroll
    for (int k = 0; k < DIM; k++) {
        mx = fmaf(accf[k], lk[k * 48 + j], mx);
        mi = fmaf(h[k],   lrk[k * 48 + j], mi);
    }

    int d = lane & 15;
    float xz = __shfl(mx, d),      rz = __shfl(mi, d);
    float xr = __shfl(mx, d + 16), rr = __shfl(mi, d + 16);
    float xh = __shfl(mx, d + 32), rh = __shfl(mi, d + 32);
    float z  = fast_sigmoid(xz + rz);
    float r  = fast_sigmoid(xr + rr);
    float hh = fast_tanh(xh + r * rh);
    float hn = z * h[d] + (1.0f - z) * hh;

    if (lane < DIM) ls[(size_t)l * DIM + lane] = hn;

    float hf[DIM];
    #pragma unroll
    for (int k = 0; k < DIM; k++) hf[k] = __shfl(hn, k);
    if (lane < DIM) {
        float mh = pb[32 + lane];
        #pragma unroll
        for (int k = 0; k < DIM; k++) mh = fmaf(hf[k], kk[k * 48 + 32 + lane], mh);
        unsigned short* rec = lrec + (size_t)l * 32;
        int q = lane >> 2, idx = lane & 3;
        rec[q * 8 + idx]     = bf16_1(hn);
        rec[q * 8 + 4 + idx] = bf16_1(mh);
    }
}

extern "C" void kernel_launch(void* const* d_in, const int* in_sizes, int n_in,
                              void* d_out, int out_size, void* d_ws, size_t ws_size,
                              hipStream_t stream)
{
    const float* flow_traffic = (const float*)d_in[0];
    const float* flow_packets = (const float*)d_in[1];
    const float* flow_pktsize = (const float*)d_in[2];
    const float* flow_type    = (const float*)d_in[3];
    const float* link_cap     = (const float*)d_in[4];
    const int*   l2p          = (const int*)d_in[5];
    const int*   p2l          = (const int*)d_in[6];
    const float* fe_w1 = (const float*)d_in[7];
    const float* fe_b1 = (const float*)d_in[8];
    const float* fe_w2 = (const float*)d_in[9];
    const float* fe_b2 = (const float*)d_in[10];
    const float* le_w1 = (const float*)d_in[11];
    const float* le_b1 = (const float*)d_in[12];
    const float* le_w2 = (const float*)d_in[13];
    const float* le_b2 = (const float*)d_in[14];
    const float* pgru_k  = (const float*)d_in[15];
    const float* pgru_rk = (const float*)d_in[16];
    const float* pgru_b  = (const float*)d_in[17];
    const float* lgru_k  = (const float*)d_in[18];
    const float* lgru_rk = (const float*)d_in[19];
    const float* lgru_b  = (const float*)d_in[20];
    const float* ro_w1 = (const float*)d_in[21];
    const float* ro_b1 = (const float*)d_in[22];
    const float* ro_w2 = (const float*)d_in[23];
    const float* ro_b2 = (const float*)d_in[24];
    const float* ro_w3 = (const float*)d_in[25];
    const float* ro_b3 = (const float*)d_in[26];
    float* out = (float*)d_out;

    char* ws = (char*)d_ws;
    unsigned short* seq   = (unsigned short*)ws;
    float*          ls    = (float*)(ws + SEQ_BYTES);
    unsigned short* lrec  = (unsigned short*)(ws + SEQ_BYTES + LS_BYTES);
    unsigned int*   p2lpE = (unsigned int*)(ws + SEQ_BYTES + LS_BYTES + LREC_BYTES);
    unsigned int*   p2lpO = (unsigned int*)(ws + SEQ_BYTES + LS_BYTES + LREC_BYTES + P2L_BYTES);
    uint4*          wtab  = (uint4*)(ws + SEQ_BYTES + LS_BYTES + LREC_BYTES + 2 * P2L_BYTES);

    k_pack<<<(N_LINKS * MAX_PL + 255) / 256, 256, 0, stream>>>(p2l, p2lpE, p2lpO);
    k_init_wtab<<<1, 64, 0, stream>>>(pgru_rk, pgru_k, pgru_b, ro_w1, ro_b1, wtab);
    k_init_links<<<N_LINKS, 64, 0, stream>>>(flow_traffic, link_cap, p2l,
        le_w1, le_b1, le_w2, le_b2, pgru_k, pgru_b, ls, lrec);
    k_init_paths<<<(N_PATHS + 255) / 256, 256, 0, stream>>>(flow_traffic,
        flow_packets, flow_pktsize, flow_type, fe_w1, fe_b1, fe_w2, fe_b2, seq);

    for (int it = 0; it < ITERS - 1; ++it) {
        int ps = (it & 1) ? 9 : 8;
        int cs = (it & 1) ? 8 : 9;
        k_paths<<<(N_PATHS / 16) / 4, 256, 0, stream>>>(l2p, lrec, wtab,
            seq, ps, cs);
        k_links<<<N_LINKS / 4, 256, 0, stream>>>((it & 1) ? p2lpO : p2lpE,
            seq, lgru_k, lgru_rk, lgru_b, pgru_k, pgru_b, ls, lrec);
    }
    // final iteration (it=7, ps=9): GRU + fused readout, no seq writes, no k_links
    k_paths_last<<<(N_PATHS / 16) / 4, 256, 0, stream>>>(l2p, lrec, wtab,
        seq, link_cap, ro_w2, ro_b2, ro_w3, ro_b3, out, 9);
}

// Round 10
// 534.392 us; speedup vs baseline: 1.0507x; 1.0068x over previous
//
#include <hip/hip_runtime.h>
#include <hip/hip_bf16.h>
#include <math.h>

#define N_PATHS  200000
#define PATH_LEN 8
#define N_LINKS  20000
#define MAX_PL   100
#define DIM      16
#define ITERS    8

typedef __attribute__((ext_vector_type(8))) short bf16x8;
typedef __attribute__((ext_vector_type(4))) float f32x4;

// ws layout (bytes):
//   seq  : ushort[10][N_PATHS][16] = 64,000,000 (bf16 states; slots 1..7 steps, 8/9 prev/cur rotation)
//   ls   : float [N_LINKS][16]     =  1,280,000 (link_state fp32)
//   lrec : ushort[N_LINKS][32]     =  1,280,000 (64-B rec per link: quad g: x[4g..4g+3] | mh[4g..4g+3])
//   p2lpE: uint  [N_LINKS*MAX_PL]  =  8,000,000
//   p2lpO: uint  [N_LINKS*MAX_PL]  =  8,000,000
//   wtab : uint4 [10][64]          =     10,240 (per-lane frags: Az Ar Ah A1 Cz Cr Ch C1 A2 C2)
#define SEQ_BYTES  64000000ull
#define LS_BYTES   1280000ull
#define LREC_BYTES 1280000ull
#define P2L_BYTES  8000000ull
#define SLOT_BYTES 6400000u   // N_PATHS * 16 * 2

__device__ __forceinline__ float fast_sigmoid(float x) {
    return __builtin_amdgcn_rcpf(1.0f + __expf(-x));
}
__device__ __forceinline__ float fast_tanh(float x) {
    float ax = fabsf(x);
    float t  = __expf(-2.0f * ax);
    float r  = (1.0f - t) * __builtin_amdgcn_rcpf(1.0f + t);
    return copysignf(r, x);
}
// softplus = max(x,0) + ln2 * log2(1 + exp2(-|x|*log2e))
__device__ __forceinline__ float fast_softplus(float x) {
    float e = __builtin_amdgcn_exp2f(-fabsf(x) * 1.44269504f);
    float lg = __builtin_amdgcn_logf(1.0f + e);   // log2
    return fmaxf(x, 0.0f) + 0.69314718f * lg;
}
__device__ __forceinline__ float bflo(unsigned int u) {
    union { unsigned int i; float f; } c; c.i = u << 16; return c.f;
}
__device__ __forceinline__ float bfhi(unsigned int u) {
    union { unsigned int i; float f; } c; c.i = u & 0xffff0000u; return c.f;
}
__device__ __forceinline__ unsigned int pk_bf16(float lo, float hi) {
    unsigned int r;
    asm("v_cvt_pk_bf16_f32 %0, %1, %2" : "=v"(r) : "v"(lo), "v"(hi));
    return r;
}
__device__ __forceinline__ unsigned short bf16_1(float v) {
    return (unsigned short)(pk_bf16(v, v) & 0xffffu);
}

union U8 { unsigned int u[4]; bf16x8 v; };
union UF4 { uint4 u; f32x4 f; };

// ---------------- pack p2l into two slot-resolved variants ----------------
__global__ __launch_bounds__(256) void k_pack(const int* __restrict__ p2l,
                                              unsigned int* __restrict__ outE,
                                              unsigned int* __restrict__ outO)
{
    int i = blockIdx.x * 256 + threadIdx.x;
    if (i < N_LINKS * MAX_PL) {
        unsigned int pi = (unsigned int)p2l[2 * i];
        unsigned int si = (unsigned int)p2l[2 * i + 1];
        unsigned int sE = (si == 0) ? 8u : ((si == 8) ? 9u : si);
        unsigned int sO = (si == 0) ? 9u : ((si == 8) ? 8u : si);
        outE[i] = (sE << 18) | pi;
        outO[i] = (sO << 18) | pi;
    }
}

// ---------------- init: per-lane MFMA fragment/bias table ----------------
// wtab[k][lane], k: 0=Az 1=Ar 2=Ah 3=A1 4=Cz 5=Cr 6=Ch 7=C1 8=A2 9=C2
__global__ __launch_bounds__(64) void k_init_wtab(
    const float* __restrict__ rk, const float* __restrict__ kk,
    const float* __restrict__ b,
    const float* __restrict__ w1, const float* __restrict__ b1,
    const float* __restrict__ w2, const float* __restrict__ b2,
    uint4* __restrict__ wtab)
{
    int l = threadIdx.x;
    int pr = l & 15, g = l >> 4, kq = g * 4;
    U8 Az, Ar, Ah, A1, A2;
    #pragma unroll
    for (int i = 0; i < 2; i++) {
        int k0 = (kq + 2 * i) * 48, k1 = (kq + 2 * i + 1) * 48;
        Az.u[i]     = pk_bf16(rk[k0 + pr],      rk[k1 + pr]);
        Az.u[2 + i] = pk_bf16(kk[k0 + pr],      kk[k1 + pr]);
        Ar.u[i]     = pk_bf16(rk[k0 + 16 + pr], rk[k1 + 16 + pr]);
        Ar.u[2 + i] = pk_bf16(kk[k0 + 16 + pr], kk[k1 + 16 + pr]);
        Ah.u[i]     = pk_bf16(rk[k0 + 32 + pr], rk[k1 + 32 + pr]);
        Ah.u[2 + i] = 0;
        A1.u[i]     = (pr < 8) ? pk_bf16(w1[(kq + 2 * i) * 8 + pr],
                                         w1[(kq + 2 * i + 1) * 8 + pr]) : 0u;
        A1.u[2 + i] = 0;
        // layer2: A2[m=pr][k<8] = w2[k][pr] for pr<4 (k = kq+2i, kq+2i+1 < 8)
        A2.u[i]     = (pr < 4 && kq + 2 * i + 1 < 8)
                        ? pk_bf16(w2[(kq + 2 * i) * 4 + pr],
                                  w2[(kq + 2 * i + 1) * 4 + pr]) : 0u;
        A2.u[2 + i] = 0;
    }
    UF4 Cz, Cr, Ch, C1, C2;
    #pragma unroll
    for (int r = 0; r < 4; r++) {
        Cz.f[r] = b[kq + r]      + b[48 + kq + r];
        Cr.f[r] = b[16 + kq + r] + b[64 + kq + r];
        Ch.f[r] = b[80 + kq + r];
        C1.f[r] = (kq + r < 8) ? b1[kq + r] : 0.0f;
        C2.f[r] = (kq + r < 4) ? b2[kq + r] : 0.0f;
    }
    wtab[0 * 64 + l] = make_uint4(Az.u[0], Az.u[1], Az.u[2], Az.u[3]);
    wtab[1 * 64 + l] = make_uint4(Ar.u[0], Ar.u[1], Ar.u[2], Ar.u[3]);
    wtab[2 * 64 + l] = make_uint4(Ah.u[0], Ah.u[1], Ah.u[2], Ah.u[3]);
    wtab[3 * 64 + l] = make_uint4(A1.u[0], A1.u[1], A1.u[2], A1.u[3]);
    wtab[4 * 64 + l] = Cz.u;
    wtab[5 * 64 + l] = Cr.u;
    wtab[6 * 64 + l] = Ch.u;
    wtab[7 * 64 + l] = C1.u;
    wtab[8 * 64 + l] = make_uint4(A2.u[0], A2.u[1], A2.u[2], A2.u[3]);
    wtab[9 * 64 + l] = C2.u;
}

// ---------------- init: link load -> link_state -> ls + lrec ----------------
__global__ __launch_bounds__(64) void k_init_links(
    const float* __restrict__ traffic, const float* __restrict__ cap,
    const int* __restrict__ p2l,
    const float* __restrict__ le_w1, const float* __restrict__ le_b1,
    const float* __restrict__ le_w2, const float* __restrict__ le_b2,
    const float* __restrict__ kk, const float* __restrict__ pb,
    float* __restrict__ ls, unsigned short* __restrict__ lrec)
{
    int l = blockIdx.x;
    int lane = threadIdx.x;
    float s = 0.0f;
    for (int j = lane; j < MAX_PL; j += 64) {
        int p = p2l[(size_t)(l * MAX_PL + j) * 2 + 0];
        s += traffic[p];
    }
    #pragma unroll
    for (int off = 32; off > 0; off >>= 1) s += __shfl_xor(s, off);

    float c = cap[l];
    float f0 = c * 0.1f;
    float f1 = s / (c * 1e9f);

    float h1[DIM];
    #pragma unroll
    for (int d = 0; d < DIM; d++)
        h1[d] = fmaxf(f0 * le_w1[d] + f1 * le_w1[DIM + d] + le_b1[d], 0.0f);

    float h2[DIM];
    #pragma unroll
    for (int d = 0; d < DIM; d++) {
        float a = le_b2[d];
        #pragma unroll
        for (int k = 0; k < DIM; k++) a = fmaf(h1[k], le_w2[k * DIM + d], a);
        h2[d] = fmaxf(a, 0.0f);
    }
    if (lane < DIM) ls[(size_t)l * DIM + lane] = h2[lane];
    if (lane < DIM) {
        float mh = pb[32 + lane];
        #pragma unroll
        for (int k = 0; k < DIM; k++) mh = fmaf(h2[k], kk[k * 48 + 32 + lane], mh);
        unsigned short* rec = lrec + (size_t)l * 32;
        int q = lane >> 2, idx = lane & 3;
        rec[q * 8 + idx]     = bf16_1(h2[lane]);
        rec[q * 8 + 4 + idx] = bf16_1(mh);
    }
}

// ---------------- init: path_state -> seq slot 8 (bf16) ----------------
__global__ __launch_bounds__(256) void k_init_paths(
    const float* __restrict__ traffic, const float* __restrict__ packets,
    const float* __restrict__ pktsize, const float* __restrict__ ftype,
    const float* __restrict__ fe_w1, const float* __restrict__ fe_b1,
    const float* __restrict__ fe_w2, const float* __restrict__ fe_b2,
    unsigned short* __restrict__ seq)
{
    int p = blockIdx.x * blockDim.x + threadIdx.x;
    if (p >= N_PATHS) return;
    float f[5];
    f[0] = traffic[p] * 0.0001f;
    f[1] = packets[p] * 0.01f;
    f[2] = pktsize[p] * 0.001f;
    f[3] = ftype[p * 2 + 0];
    f[4] = ftype[p * 2 + 1];

    float h1[DIM];
    #pragma unroll
    for (int d = 0; d < DIM; d++) {
        float a = fe_b1[d];
        #pragma unroll
        for (int k = 0; k < 5; k++) a = fmaf(f[k], fe_w1[k * DIM + d], a);
        h1[d] = fmaxf(a, 0.0f);
    }
    float h2[DIM];
    #pragma unroll
    for (int d = 0; d < DIM; d++) {
        float a = fe_b2[d];
        #pragma unroll
        for (int k = 0; k < DIM; k++) a = fmaf(h1[k], fe_w2[k * DIM + d], a);
        h2[d] = fmaxf(a, 0.0f);
    }
    unsigned int pkd[8];
    #pragma unroll
    for (int q = 0; q < 8; q++) pkd[q] = pk_bf16(h2[2 * q], h2[2 * q + 1]);
    uint4* out = (uint4*)(seq + ((size_t)8 * N_PATHS + p) * DIM);
    out[0] = make_uint4(pkd[0], pkd[1], pkd[2], pkd[3]);
    out[1] = make_uint4(pkd[4], pkd[5], pkd[6], pkd[7]);
}

// ---------------- per-iteration: path GRU via MFMA, 16 paths/wave ----------------
__global__ __launch_bounds__(256, 8) void k_paths(
    const int* __restrict__ l2p, const unsigned short* __restrict__ lrec,
    const uint4* __restrict__ wtab,
    unsigned short* __restrict__ seq, int ps, int cs)
{
    int l = threadIdx.x & 63;
    int wave = (blockIdx.x * 256 + threadIdx.x) >> 6;   // 0..12499 exact
    int pr = l & 15;
    int g  = l >> 4;
    int p  = wave * 16 + pr;

    // per-lane constant frags/biases: 6 coalesced 16-B loads
    U8 Az, Ar, Ah;
    {
        uint4 a = wtab[0 * 64 + l], r = wtab[1 * 64 + l], h = wtab[2 * 64 + l];
        Az.u[0] = a.x; Az.u[1] = a.y; Az.u[2] = a.z; Az.u[3] = a.w;
        Ar.u[0] = r.x; Ar.u[1] = r.y; Ar.u[2] = r.z; Ar.u[3] = r.w;
        Ah.u[0] = h.x; Ah.u[1] = h.y; Ah.u[2] = h.z; Ah.u[3] = h.w;
    }
    UF4 Czu, Cru, Chu;
    Czu.u = wtab[4 * 64 + l]; Cru.u = wtab[5 * 64 + l]; Chu.u = wtab[6 * 64 + l];
    f32x4 Cz = Czu.f, Cr = Cru.f, Ch = Chu.f;

    int4 ia = *(const int4*)(l2p + (size_t)p * 8);
    int4 ib = *(const int4*)(l2p + (size_t)p * 8 + 4);
#define IDX(t) ((t) == 0 ? ia.x : (t) == 1 ? ia.y : (t) == 2 ? ia.z : (t) == 3 ? ia.w : \
                (t) == 4 ? ib.x : (t) == 5 ? ib.y : (t) == 6 ? ib.z : ib.w)

    const char* lrecc = (const char*)lrec;
    char* seqc = (char*)seq;
    unsigned g16 = (unsigned)(g * 16);
    unsigned sbase = (unsigned)p * 32u + (unsigned)(g * 8);
    unsigned csoff = (unsigned)cs * SLOT_BYTES + sbase;

    uint4 X[8];
    #pragma unroll
    for (int t = 0; t < 8; t++)
        X[t] = *(const uint4*)(lrecc + (unsigned)IDX(t) * 64u + g16);

    float h0, h1, h2, h3;
    U8 B;
    {
        uint2 hp = *(const uint2*)(seqc + ((unsigned)ps * SLOT_BYTES + sbase));
        h0 = bflo(hp.x); h1 = bfhi(hp.x); h2 = bflo(hp.y); h3 = bfhi(hp.y);
        B.u[0] = hp.x; B.u[1] = hp.y;
    }

#define STEPX(t, soff) { \
    B.u[2] = X[t].x; B.u[3] = X[t].y; \
    f32x4 az = __builtin_amdgcn_mfma_f32_16x16x32_bf16(Az.v, B.v, Cz, 0, 0, 0); \
    f32x4 ar = __builtin_amdgcn_mfma_f32_16x16x32_bf16(Ar.v, B.v, Cr, 0, 0, 0); \
    f32x4 ah = __builtin_amdgcn_mfma_f32_16x16x32_bf16(Ah.v, B.v, Ch, 0, 0, 0); \
    float z0 = fast_sigmoid(az[0]), z1 = fast_sigmoid(az[1]); \
    float z2 = fast_sigmoid(az[2]), z3 = fast_sigmoid(az[3]); \
    float r0 = fast_sigmoid(ar[0]), r1 = fast_sigmoid(ar[1]); \
    float r2 = fast_sigmoid(ar[2]), r3 = fast_sigmoid(ar[3]); \
    float q0 = fast_tanh(bflo(X[t].z) + r0 * ah[0]); \
    float q1 = fast_tanh(bfhi(X[t].z) + r1 * ah[1]); \
    float q2 = fast_tanh(bflo(X[t].w) + r2 * ah[2]); \
    float q3 = fast_tanh(bfhi(X[t].w) + r3 * ah[3]); \
    h0 = z0 * h0 + (1.0f - z0) * q0; \
    h1 = z1 * h1 + (1.0f - z1) * q1; \
    h2 = z2 * h2 + (1.0f - z2) * q2; \
    h3 = z3 * h3 + (1.0f - z3) * q3; \
    unsigned int p01 = pk_bf16(h0, h1), p23 = pk_bf16(h2, h3); \
    *(uint2*)(seqc + (soff)) = make_uint2(p01, p23); \
    B.u[0] = p01; B.u[1] = p23; }

    STEPX(0, 1u * SLOT_BYTES + sbase)
    STEPX(1, 2u * SLOT_BYTES + sbase)
    STEPX(2, 3u * SLOT_BYTES + sbase)
    STEPX(3, 4u * SLOT_BYTES + sbase)
    STEPX(4, 5u * SLOT_BYTES + sbase)
    STEPX(5, 6u * SLOT_BYTES + sbase)
    STEPX(6, 7u * SLOT_BYTES + sbase)
    STEPX(7, csoff)
#undef STEPX
}

// ---------------- final iteration: path GRU + fused readout, NO seq writes ----------------
// Readout layer 1 AND layer 2 via MFMA (A1/C1 and A2/C2 from wtab); only g==0's
// d2 rows 0..3 are valid (A2/C2 zero elsewhere) and only g==0 writes out.
__global__ __launch_bounds__(256, 6) void k_paths_last(
    const int* __restrict__ l2p, const unsigned short* __restrict__ lrec,
    const uint4* __restrict__ wtab,
    const unsigned short* __restrict__ seq,
    const float* __restrict__ cap,
    const float* __restrict__ w3, const float* __restrict__ b3,
    float* __restrict__ out, int ps)
{
    int l = threadIdx.x & 63;
    int wave = (blockIdx.x * 256 + threadIdx.x) >> 6;
    int pr = l & 15;
    int g  = l >> 4;
    int p  = wave * 16 + pr;

    U8 Az, Ar, Ah, A1, A2;
    {
        uint4 a = wtab[0 * 64 + l], r = wtab[1 * 64 + l];
        uint4 h = wtab[2 * 64 + l], o1 = wtab[3 * 64 + l], o2 = wtab[8 * 64 + l];
        Az.u[0] = a.x; Az.u[1] = a.y; Az.u[2] = a.z; Az.u[3] = a.w;
        Ar.u[0] = r.x; Ar.u[1] = r.y; Ar.u[2] = r.z; Ar.u[3] = r.w;
        Ah.u[0] = h.x; Ah.u[1] = h.y; Ah.u[2] = h.z; Ah.u[3] = h.w;
        A1.u[0] = o1.x; A1.u[1] = o1.y; A1.u[2] = o1.z; A1.u[3] = o1.w;
        A2.u[0] = o2.x; A2.u[1] = o2.y; A2.u[2] = o2.z; A2.u[3] = o2.w;
    }
    UF4 Czu, Cru, Chu, C1u, C2u;
    Czu.u = wtab[4 * 64 + l]; Cru.u = wtab[5 * 64 + l];
    Chu.u = wtab[6 * 64 + l]; C1u.u = wtab[7 * 64 + l]; C2u.u = wtab[9 * 64 + l];
    f32x4 Cz = Czu.f, Cr = Cru.f, Ch = Chu.f, C1 = C1u.f, C2 = C2u.f;

    float W3[4], B3v;
    #pragma unroll
    for (int j = 0; j < 4; j++) W3[j] = w3[j];
    B3v = b3[0];

    int4 ia = *(const int4*)(l2p + (size_t)p * 8);
    int4 ib = *(const int4*)(l2p + (size_t)p * 8 + 4);

    const char* lrecc = (const char*)lrec;
    const char* seqc = (const char*)seq;
    unsigned g16 = (unsigned)(g * 16);
    unsigned sbase = (unsigned)p * 32u + (unsigned)(g * 8);

    uint4 X[8];
    float capv[8];
    #pragma unroll
    for (int t = 0; t < 8; t++) {
        int li = IDX(t);
        X[t] = *(const uint4*)(lrecc + (unsigned)li * 64u + g16);
        capv[t] = cap[li];
    }

    float h0, h1, h2, h3;
    U8 B;
    {
        uint2 hp = *(const uint2*)(seqc + ((unsigned)ps * SLOT_BYTES + sbase));
        h0 = bflo(hp.x); h1 = bfhi(hp.x); h2 = bflo(hp.y); h3 = bfhi(hp.y);
        B.u[0] = hp.x; B.u[1] = hp.y;
    }
    U8 Bro;
    Bro.u[2] = 0; Bro.u[3] = 0;
    float delay = 0.0f;

#define STEPL(t) { \
    B.u[2] = X[t].x; B.u[3] = X[t].y; \
    f32x4 az = __builtin_amdgcn_mfma_f32_16x16x32_bf16(Az.v, B.v, Cz, 0, 0, 0); \
    f32x4 ar = __builtin_amdgcn_mfma_f32_16x16x32_bf16(Ar.v, B.v, Cr, 0, 0, 0); \
    f32x4 ah = __builtin_amdgcn_mfma_f32_16x16x32_bf16(Ah.v, B.v, Ch, 0, 0, 0); \
    float z0 = fast_sigmoid(az[0]), z1 = fast_sigmoid(az[1]); \
    float z2 = fast_sigmoid(az[2]), z3 = fast_sigmoid(az[3]); \
    float r0 = fast_sigmoid(ar[0]), r1 = fast_sigmoid(ar[1]); \
    float r2 = fast_sigmoid(ar[2]), r3 = fast_sigmoid(ar[3]); \
    float q0 = fast_tanh(bflo(X[t].z) + r0 * ah[0]); \
    float q1 = fast_tanh(bfhi(X[t].z) + r1 * ah[1]); \
    float q2 = fast_tanh(bflo(X[t].w) + r2 * ah[2]); \
    float q3 = fast_tanh(bfhi(X[t].w) + r3 * ah[3]); \
    h0 = z0 * h0 + (1.0f - z0) * q0; \
    h1 = z1 * h1 + (1.0f - z1) * q1; \
    h2 = z2 * h2 + (1.0f - z2) * q2; \
    h3 = z3 * h3 + (1.0f - z3) * q3; \
    unsigned int p01 = pk_bf16(h0, h1), p23 = pk_bf16(h2, h3); \
    B.u[0] = p01; B.u[1] = p23; \
    Bro.u[0] = p01; Bro.u[1] = p23; \
    f32x4 d1 = __builtin_amdgcn_mfma_f32_16x16x32_bf16(A1.v, Bro.v, C1, 0, 0, 0); \
    float e0 = fmaxf(d1[0], 0.0f), e1 = fmaxf(d1[1], 0.0f); \
    float e2 = fmaxf(d1[2], 0.0f), e3 = fmaxf(d1[3], 0.0f); \
    U8 B2; \
    B2.u[0] = pk_bf16(e0, e1); B2.u[1] = pk_bf16(e2, e3); \
    B2.u[2] = 0; B2.u[3] = 0; \
    f32x4 d2 = __builtin_amdgcn_mfma_f32_16x16x32_bf16(A2.v, B2.v, C2, 0, 0, 0); \
    float s0 = fmaxf(d2[0], 0.0f), s1 = fmaxf(d2[1], 0.0f); \
    float s2 = fmaxf(d2[2], 0.0f), s3 = fmaxf(d2[3], 0.0f); \
    float o = B3v; \
    o = fmaf(s0, W3[0], o); o = fmaf(s1, W3[1], o); \
    o = fmaf(s2, W3[2], o); o = fmaf(s3, W3[3], o); \
    o = fast_softplus(o); \
    delay += o * __builtin_amdgcn_rcpf(capv[t]); }

    STEPL(0) STEPL(1) STEPL(2) STEPL(3)
    STEPL(4) STEPL(5) STEPL(6) STEPL(7)
#undef STEPL
#undef IDX

    if (g == 0) out[p] = delay;
}

// ---------------- per-iteration: link aggregate + link GRU + lrec ----------------
__global__ __launch_bounds__(256) void k_links(
    const unsigned int* __restrict__ p2lp, const unsigned short* __restrict__ seq,
    const float* __restrict__ lk, const float* __restrict__ lrk,
    const float* __restrict__ lb,
    const float* __restrict__ kk, const float* __restrict__ pb,
    float* ls, unsigned short* __restrict__ lrec)
{
    int lane = threadIdx.x & 63;
    int l = blockIdx.x * 4 + (threadIdx.x >> 6);
    size_t base = (size_t)l * MAX_PL;
    int half = lane & 1;
    int r0 = lane >> 1;

    unsigned int e0 = p2lp[base + r0];
    unsigned int e1 = p2lp[base + r0 + 32];
    unsigned int e2 = p2lp[base + r0 + 64];

    const unsigned short* sh = seq + half * 8;
    unsigned int pi, si;
    pi = e0 & 0x3FFFFu; si = e0 >> 18;
    uint4 a0 = *(const uint4*)(sh + ((size_t)si * N_PATHS + pi) * DIM);
    pi = e1 & 0x3FFFFu; si = e1 >> 18;
    uint4 a1 = *(const uint4*)(sh + ((size_t)si * N_PATHS + pi) * DIM);
    pi = e2 & 0x3FFFFu; si = e2 >> 18;
    uint4 a2 = *(const uint4*)(sh + ((size_t)si * N_PATHS + pi) * DIM);

    float acc[8];
    #pragma unroll
    for (int i = 0; i < 8; i++) acc[i] = 0.0f;
    unsigned int selLo = 0x00003F80u;
    unsigned int selHi = 0x3F800000u;

#define DOTU(u, i0) \
    asm("v_dot2_f32_bf16 %0, %1, %2, %0" : "+v"(acc[i0]) : "v"(u), "v"(selLo)); \
    asm("v_dot2_f32_bf16 %0, %1, %2, %0" : "+v"(acc[i0 + 1]) : "v"(u), "v"(selHi));
#define DOT8(a) DOTU(a.x, 0) DOTU(a.y, 2) DOTU(a.z, 4) DOTU(a.w, 6)

    DOT8(a0) DOT8(a1) DOT8(a2)
    if (r0 < 4) {
        unsigned int e3 = p2lp[base + r0 + 96];
        pi = e3 & 0x3FFFFu; si = e3 >> 18;
        uint4 a3 = *(const uint4*)(sh + ((size_t)si * N_PATHS + pi) * DIM);
        DOT8(a3)
    }
#undef DOTU
#undef DOT8

    float v4[4];
    {
        int sel = (lane & 2) ? 4 : 0;
        #pragma unroll
        for (int i = 0; i < 4; i++)
            v4[i] = acc[sel + i] + __shfl_xor(acc[(4 - sel) + i], 2);
    }
    float v2[2];
    {
        int sel = (lane & 4) ? 2 : 0;
        #pragma unroll
        for (int i = 0; i < 2; i++)
            v2[i] = v4[sel + i] + __shfl_xor(v4[(2 - sel) + i], 4);
    }
    float s;
    {
        int sel = (lane & 8) ? 1 : 0;
        s = v2[sel] + __shfl_xor(v2[1 - sel], 8);
    }
    s += __shfl_xor(s, 16);
    s += __shfl_xor(s, 32);

    float accf[16];
    #pragma unroll
    for (int k = 0; k < 16; k++) {
        int src = ((k >> 3) & 1) | (((k >> 2) & 1) << 1) | (((k >> 1) & 1) << 2) | ((k & 1) << 3);
        accf[k] = __shfl(s, src);
    }

    float h[DIM];
    #pragma unroll
    for (int d = 0; d < DIM; d++) h[d] = ls[(size_t)l * DIM + d];

    int j = (lane < 48) ? lane : 0;
    float mx = lb[j];
    float mi = lb[48 + j];
    #pragma unroll
    for (int k = 0; k < DIM; k++) {
        mx = fmaf(accf[k], lk[k * 48 + j], mx);
        mi = fmaf(h[k],   lrk[k * 48 + j], mi);
    }

    int d = lane & 15;
    float xz = __shfl(mx, d),      rz = __shfl(mi, d);
    float xr = __shfl(mx, d + 16), rr = __shfl(mi, d + 16);
    float xh = __shfl(mx, d + 32), rh = __shfl(mi, d + 32);
    float z  = fast_sigmoid(xz + rz);
    float r  = fast_sigmoid(xr + rr);
    float hh = fast_tanh(xh + r * rh);
    float hn = z * h[d] + (1.0f - z) * hh;

    if (lane < DIM) ls[(size_t)l * DIM + lane] = hn;

    float hf[DIM];
    #pragma unroll
    for (int k = 0; k < DIM; k++) hf[k] = __shfl(hn, k);
    if (lane < DIM) {
        float mh = pb[32 + lane];
        #pragma unroll
        for (int k = 0; k < DIM; k++) mh = fmaf(hf[k], kk[k * 48 + 32 + lane], mh);
        unsigned short* rec = lrec + (size_t)l * 32;
        int q = lane >> 2, idx = lane & 3;
        rec[q * 8 + idx]     = bf16_1(hn);
        rec[q * 8 + 4 + idx] = bf16_1(mh);
    }
}

extern "C" void kernel_launch(void* const* d_in, const int* in_sizes, int n_in,
                              void* d_out, int out_size, void* d_ws, size_t ws_size,
                              hipStream_t stream)
{
    const float* flow_traffic = (const float*)d_in[0];
    const float* flow_packets = (const float*)d_in[1];
    const float* flow_pktsize = (const float*)d_in[2];
    const float* flow_type    = (const float*)d_in[3];
    const float* link_cap     = (const float*)d_in[4];
    const int*   l2p          = (const int*)d_in[5];
    const int*   p2l          = (const int*)d_in[6];
    const float* fe_w1 = (const float*)d_in[7];
    const float* fe_b1 = (const float*)d_in[8];
    const float* fe_w2 = (const float*)d_in[9];
    const float* fe_b2 = (const float*)d_in[10];
    const float* le_w1 = (const float*)d_in[11];
    const float* le_b1 = (const float*)d_in[12];
    const float* le_w2 = (const float*)d_in[13];
    const float* le_b2 = (const float*)d_in[14];
    const float* pgru_k  = (const float*)d_in[15];
    const float* pgru_rk = (const float*)d_in[16];
    const float* pgru_b  = (const float*)d_in[17];
    const float* lgru_k  = (const float*)d_in[18];
    const float* lgru_rk = (const float*)d_in[19];
    const float* lgru_b  = (const float*)d_in[20];
    const float* ro_w1 = (const float*)d_in[21];
    const float* ro_b1 = (const float*)d_in[22];
    const float* ro_w2 = (const float*)d_in[23];
    const float* ro_b2 = (const float*)d_in[24];
    const float* ro_w3 = (const float*)d_in[25];
    const float* ro_b3 = (const float*)d_in[26];
    float* out = (float*)d_out;

    char* ws = (char*)d_ws;
    unsigned short* seq   = (unsigned short*)ws;
    float*          ls    = (float*)(ws + SEQ_BYTES);
    unsigned short* lrec  = (unsigned short*)(ws + SEQ_BYTES + LS_BYTES);
    unsigned int*   p2lpE = (unsigned int*)(ws + SEQ_BYTES + LS_BYTES + LREC_BYTES);
    unsigned int*   p2lpO = (unsigned int*)(ws + SEQ_BYTES + LS_BYTES + LREC_BYTES + P2L_BYTES);
    uint4*          wtab  = (uint4*)(ws + SEQ_BYTES + LS_BYTES + LREC_BYTES + 2 * P2L_BYTES);

    k_pack<<<(N_LINKS * MAX_PL + 255) / 256, 256, 0, stream>>>(p2l, p2lpE, p2lpO);
    k_init_wtab<<<1, 64, 0, stream>>>(pgru_rk, pgru_k, pgru_b, ro_w1, ro_b1,
        ro_w2, ro_b2, wtab);
    k_init_links<<<N_LINKS, 64, 0, stream>>>(flow_traffic, link_cap, p2l,
        le_w1, le_b1, le_w2, le_b2, pgru_k, pgru_b, ls, lrec);
    k_init_paths<<<(N_PATHS + 255) / 256, 256, 0, stream>>>(flow_traffic,
        flow_packets, flow_pktsize, flow_type, fe_w1, fe_b1, fe_w2, fe_b2, seq);

    for (int it = 0; it < ITERS - 1; ++it) {
        int ps = (it & 1) ? 9 : 8;
        int cs = (it & 1) ? 8 : 9;
        k_paths<<<(N_PATHS / 16) / 4, 256, 0, stream>>>(l2p, lrec, wtab,
            seq, ps, cs);
        k_links<<<N_LINKS / 4, 256, 0, stream>>>((it & 1) ? p2lpO : p2lpE,
            seq, lgru_k, lgru_rk, lgru_b, pgru_k, pgru_b, ls, lrec);
    }
    // final iteration (it=7, ps=9): GRU + fused readout, no seq writes, no k_links
    k_paths_last<<<(N_PATHS / 16) / 4, 256, 0, stream>>>(l2p, lrec, wtab,
        seq, link_cap, ro_w3, ro_b3, out, 9);
}